// Round 1
// baseline (1118.608 us; speedup 1.0000x reference)
//
#include <hip/hip_runtime.h>
#include <math.h>

#define Hh      6
#define HD      64
#define EH      128
#define KK      16
#define SUBD    32
#define SQRT_N  128
#define D_MODEL 384
#define LN_EPS  1e-5f

// ---------------------------------------------------------------------------
// Kernel 1: routing. One block per (token, head). 128 threads.
// Computes q = x@Wq slice, LayerNorm, scores vs c_keys/c_prime_keys,
// top-16 of each (exact lax.top_k order), joint 16x16 top-16, softmax.
// Writes expert indices (int) and routing weights (float) to workspace.
// ---------------------------------------------------------------------------
__global__ __launch_bounds__(128) void route_kernel(
    const float* __restrict__ x, const float* __restrict__ Wq,
    const float* __restrict__ gamma, const float* __restrict__ beta,
    const float* __restrict__ ck, const float* __restrict__ ckp,
    int* __restrict__ idx_g, float* __restrict__ rw_g)
{
    __shared__ float xl[D_MODEL];
    __shared__ float ckl[SQRT_N * 33];   // +1-pad: bank = (n+j)%32, conflict-free
    __shared__ float ckpl[SQRT_N * 33];
    __shared__ float qpart[2][HD];
    __shared__ float qnl[HD];
    __shared__ float s1l[SQRT_N], s2l[SQRT_N];
    __shared__ float ts1[16], ts2[16];
    __shared__ int   is1[16], is2[16];
    __shared__ float jl[256];
    __shared__ float fsl[16];
    __shared__ int   eidl[16];

    const int bid   = blockIdx.x;
    const int token = bid / Hh;
    const int h     = bid % Hh;
    const int t     = threadIdx.x;

    // stage x row and key tables (global-coalesced, LDS padded)
    for (int i = t; i < D_MODEL; i += 128) xl[i] = x[token * D_MODEL + i];
    for (int i = t; i < SQRT_N * SUBD; i += 128) {
        int n = i >> 5, j = i & 31;
        ckl[n * 33 + j]  = ck[i];
        ckpl[n * 33 + j] = ckp[i];
    }
    __syncthreads();

    // q[j] = sum_r x[r] * Wq[r, h*64+j]; split r over 2 halves of the block
    {
        int j = t & 63, half = t >> 6;
        const float* wcol = Wq + h * HD + j;
        float p = 0.f;
        int r0 = half * 192;
        for (int r = r0; r < r0 + 192; ++r) p += xl[r] * wcol[(size_t)r * D_MODEL];
        qpart[half][j] = p;
    }
    __syncthreads();

    // LayerNorm over HD=64 (threads 0..63 == wave 0)
    if (t < HD) {
        float qv = qpart[0][t] + qpart[1][t];
        float sum = qv;
        for (int off = 32; off >= 1; off >>= 1) sum += __shfl_xor(sum, off, 64);
        float mu = sum * (1.f / 64.f);
        float e  = qv - mu;
        float vs = e * e;
        for (int off = 32; off >= 1; off >>= 1) vs += __shfl_xor(vs, off, 64);
        float var = vs * (1.f / 64.f);
        qnl[t] = e * rsqrtf(var + LN_EPS) * gamma[t] + beta[t];
    }
    __syncthreads();

    // scores: thread t handles key row n=t (both tables)
    {
        float a = 0.f, b2 = 0.f;
        for (int j = 0; j < SUBD; ++j) {
            a  += qnl[j]        * ckl[t * 33 + j];
            b2 += qnl[SUBD + j] * ckpl[t * 33 + j];
        }
        s1l[t] = a;
        s2l[t] = b2;
    }
    __syncthreads();

    // exact top-16 via rank (lax.top_k tie-break: lower index first)
    {
        float v1 = s1l[t], v2 = s2l[t];
        int r1 = 0, r2 = 0;
        for (int m = 0; m < SQRT_N; ++m) {
            float w1 = s1l[m], w2 = s2l[m];
            r1 += (w1 > v1) || (w1 == v1 && m < t);
            r2 += (w2 > v2) || (w2 == v2 && m < t);
        }
        if (r1 < 16) { ts1[r1] = v1; is1[r1] = t; }
        if (r2 < 16) { ts2[r2] = v2; is2[r2] = t; }
    }
    __syncthreads();

    // joint 16x16 (provably contains the reference's 64x64 top-16)
    jl[t]       = ts1[t >> 4]        + ts2[t & 15];
    jl[t + 128] = ts1[(t + 128) >> 4] + ts2[(t + 128) & 15];
    __syncthreads();
    for (int pp = 0; pp < 2; ++pp) {
        int p = t + pp * 128;
        float v = jl[p];
        int r = 0;
        for (int q = 0; q < 256; ++q) {
            float w = jl[q];
            r += (w > v) || (w == v && q < p);
        }
        if (r < 16) {
            fsl[r]  = v;
            eidl[r] = is1[p >> 4] * SQRT_N + is2[p & 15];
        }
    }
    __syncthreads();

    // softmax over the 16 selected scores (fsl[0] is the max: sorted desc)
    if (t < 16) {
        float e = expf(fsl[t] - fsl[0]);
        float s = e;
        for (int off = 8; off >= 1; off >>= 1) s += __shfl_xor(s, off, 16);
        rw_g[bid * KK + t]  = e / s;
        idx_g[bid * KK + t] = eidl[t];
    }
}

// ---------------------------------------------------------------------------
// Kernel 2: expert gather + compute (the HBM-bound term).
// One block per (token, head), 256 threads, loop over K=16 experts.
// Fully coalesced float4 loads of w_down/w_up rows.
// ---------------------------------------------------------------------------
__global__ __launch_bounds__(256) void expert_kernel(
    const float* __restrict__ x, const float* __restrict__ wdn,
    const float* __restrict__ wup, const int* __restrict__ idx_g,
    const float* __restrict__ rw_g, float* __restrict__ oh)
{
    __shared__ float xl[HD];
    __shared__ float hpart[8][EH];
    __shared__ float hl[EH];
    __shared__ float opart[16][HD];

    const int bid   = blockIdx.x;
    const int token = bid / Hh;
    const int h     = bid % Hh;
    const int t     = threadIdx.x;

    if (t < HD) xl[t] = x[token * D_MODEL + h * HD + t];
    float acc = 0.f;
    __syncthreads();

    for (int k = 0; k < KK; ++k) {
        const int   eid = idx_g[bid * KK + k];
        const float rw  = rw_g[bid * KK + k];
        const float* wd = wdn + (size_t)eid * (HD * EH);
        const float* wu = wup + (size_t)eid * (EH * HD);

        // down: hidden[e] = sum_d x[d] * wd[d,e]   (wd row-major 64x128)
        {
            int eg = t & 31, dg = t >> 5;          // 32 e-groups x 8 d-groups
            float4 p = make_float4(0.f, 0.f, 0.f, 0.f);
            for (int i = 0; i < 8; ++i) {
                int d = dg * 8 + i;
                const float4 w4 = *reinterpret_cast<const float4*>(wd + d * EH + eg * 4);
                float xd = xl[d];
                p.x += xd * w4.x; p.y += xd * w4.y; p.z += xd * w4.z; p.w += xd * w4.w;
            }
            *reinterpret_cast<float4*>(&hpart[dg][eg * 4]) = p;
        }
        __syncthreads();
        if (t < EH) {
            float hsum = 0.f;
            for (int dg = 0; dg < 8; ++dg) hsum += hpart[dg][t];
            // exact GELU: x * 0.5 * (1 + erf(x/sqrt(2))), then routing weight
            float g = hsum * 0.5f * (1.f + erff(hsum * 0.70710678118654752440f));
            hl[t] = g * rw;
        }
        __syncthreads();

        // up: out[d'] += sum_e hl[e] * wu[e,d']   (wu row-major 128x64)
        {
            int dg = t & 15, eg = t >> 4;          // 16 d-groups x 16 e-groups
            float4 p = make_float4(0.f, 0.f, 0.f, 0.f);
            for (int i = 0; i < 8; ++i) {
                int e = eg * 8 + i;
                const float4 w4 = *reinterpret_cast<const float4*>(wu + e * HD + dg * 4);
                float he = hl[e];
                p.x += he * w4.x; p.y += he * w4.y; p.z += he * w4.z; p.w += he * w4.w;
            }
            *reinterpret_cast<float4*>(&opart[eg][dg * 4]) = p;
        }
        __syncthreads();
        if (t < HD) {
            float o = 0.f;
            for (int eg = 0; eg < 16; ++eg) o += opart[eg][t];
            acc += o;
        }
        __syncthreads();
    }
    if (t < HD) oh[bid * HD + t] = acc;
}

// ---------------------------------------------------------------------------
// Kernel 3: out = out_heads(256,384) @ W_out(384,384). One block per row.
// ---------------------------------------------------------------------------
__global__ __launch_bounds__(128) void outproj_kernel(
    const float* __restrict__ oh, const float* __restrict__ Wout,
    float* __restrict__ out)
{
    __shared__ float ol[D_MODEL];
    const int r = blockIdx.x;
    const int t = threadIdx.x;
    for (int i = t; i < D_MODEL; i += 128) ol[i] = oh[r * D_MODEL + i];
    __syncthreads();
    float a0 = 0.f, a1 = 0.f, a2 = 0.f;
    for (int kk = 0; kk < D_MODEL; ++kk) {
        float ov = ol[kk];
        const float* wr = Wout + (size_t)kk * D_MODEL;
        a0 += ov * wr[t];
        a1 += ov * wr[t + 128];
        a2 += ov * wr[t + 256];
    }
    out[r * D_MODEL + t]       = a0;
    out[r * D_MODEL + t + 128] = a1;
    out[r * D_MODEL + t + 256] = a2;
}

// ---------------------------------------------------------------------------
extern "C" void kernel_launch(void* const* d_in, const int* in_sizes, int n_in,
                              void* d_out, int out_size, void* d_ws, size_t ws_size,
                              hipStream_t stream)
{
    const float* x     = (const float*)d_in[0];
    const float* Wq    = (const float*)d_in[1];
    const float* gamma = (const float*)d_in[2];
    const float* beta  = (const float*)d_in[3];
    const float* ck    = (const float*)d_in[4];
    const float* ckp   = (const float*)d_in[5];
    const float* wdn   = (const float*)d_in[6];
    const float* wup   = (const float*)d_in[7];
    const float* Wout  = (const float*)d_in[8];
    float* out = (float*)d_out;

    const int BS  = in_sizes[0] / D_MODEL;   // b*s = 256
    const int nbh = BS * Hh;                 // 1536

    char* ws = (char*)d_ws;
    int*   idx_g = (int*)ws;
    float* rw_g  = (float*)(ws + (size_t)nbh * KK * sizeof(int));
    float* oh    = (float*)(ws + (size_t)nbh * KK * (sizeof(int) + sizeof(float)));

    route_kernel<<<nbh, 128, 0, stream>>>(x, Wq, gamma, beta, ck, ckp, idx_g, rw_g);
    expert_kernel<<<nbh, 256, 0, stream>>>(x, wdn, wup, idx_g, rw_g, oh);
    outproj_kernel<<<BS, 128, 0, stream>>>(oh, Wout, out);
}